// Round 1
// baseline (620.145 us; speedup 1.0000x reference)
//
#include <hip/hip_runtime.h>
#include <cstdint>
#include <cstddef>

#define NEG_SLOPE 0.01f
#define BN_EPS 1e-5f

// ---------------- preprocessing ----------------

__global__ void zero_kernel(int* __restrict__ cnt, float* __restrict__ stats, int n) {
    int i = blockIdx.x * blockDim.x + threadIdx.x;
    if (i < n) cnt[i] = 0;
    if (i < 1024) stats[i] = 0.0f;
}

__global__ void count_kernel(const int* __restrict__ dst, int* __restrict__ cnt, int E) {
    for (int e = blockIdx.x * blockDim.x + threadIdx.x; e < E; e += gridDim.x * blockDim.x)
        atomicAdd(&cnt[dst[e]], 1);
}

// Hillis-Steele block scan: writes exclusive prefix into out, block total into partials.
__global__ __launch_bounds__(1024) void scan_block_kernel(const int* __restrict__ in,
                                                          int* __restrict__ out,
                                                          int* __restrict__ partials, int n) {
    __shared__ int sm[1024];
    int tid = threadIdx.x;
    int i = blockIdx.x * 1024 + tid;
    int v = (i < n) ? in[i] : 0;
    int x = v;
    sm[tid] = x;
    __syncthreads();
    for (int off = 1; off < 1024; off <<= 1) {
        int y = (tid >= off) ? sm[tid - off] : 0;
        __syncthreads();
        x += y;
        sm[tid] = x;
        __syncthreads();
    }
    if (i < n) out[i] = x - v;           // exclusive
    if (tid == 1023 && partials) partials[blockIdx.x] = x;
}

__global__ void scan_add_kernel(int* __restrict__ rowptr, const int* __restrict__ pofs,
                                int n, int E) {
    int i = blockIdx.x * blockDim.x + threadIdx.x;
    if (i < n) rowptr[i] += pofs[i >> 10];
    if (i == 0) rowptr[n] = E;
}

__global__ void dinv_kernel(const int* __restrict__ cnt, const int* __restrict__ rowptr,
                            float* __restrict__ dinv, int* __restrict__ wofs, int n) {
    int i = blockIdx.x * blockDim.x + threadIdx.x;
    if (i < n) {
        dinv[i] = rsqrtf((float)(cnt[i] + 1));   // +1 = self-loop
        wofs[i] = rowptr[i];
    }
}

__global__ void scatter_kernel(const int* __restrict__ src, const int* __restrict__ dst,
                               int* __restrict__ wofs, int* __restrict__ csr, int E) {
    for (int e = blockIdx.x * blockDim.x + threadIdx.x; e < E; e += gridDim.x * blockDim.x) {
        int d = dst[e];
        int slot = atomicAdd(&wofs[d], 1);
        csr[slot] = src[e];
    }
}

// ---------------- GEMM (f32, LDS-tiled, optional fused BN-affine on A) ----------------
// H[n x M] = bn(X)[n x K] @ W[K x M];  bn(x)_k = x_k * bnS[k] + bnT[k] when BN.

template <int K, int M, int KC, int RPT, bool BN>
__global__ __launch_bounds__(256) void gemm_kernel(const float* __restrict__ X,
                                                   const float* __restrict__ W,
                                                   const float* __restrict__ bnS,
                                                   const float* __restrict__ bnT,
                                                   float* __restrict__ H, int n) {
    constexpr int COLG = M / 4;            // thread-columns (each does float4)
    constexpr int ROWG = 256 / COLG;       // thread-rows
    constexpr int RB = ROWG * RPT;         // rows per block
    __shared__ float Xl[RB][KC + 4];       // +4 pad keeps 16B alignment, breaks bank stride
    __shared__ float Wl[KC][M];

    const int t = threadIdx.x;
    const int colg = t % COLG;
    const int rowg = t / COLG;
    const int row0 = blockIdx.x * RB;

    float4 acc[RPT];
#pragma unroll
    for (int r = 0; r < RPT; ++r) acc[r] = make_float4(0.f, 0.f, 0.f, 0.f);

    for (int kc = 0; kc < K; kc += KC) {
        // stage W chunk (contiguous region)
        {
            const float4* Wg = (const float4*)(W + (size_t)kc * M);
            float4* Ws = (float4*)(&Wl[0][0]);
            for (int idx = t; idx < KC * M / 4; idx += 256) Ws[idx] = Wg[idx];
        }
        // stage X chunk, applying BN affine on load
        {
            constexpr int C4 = KC / 4;
            for (int idx = t; idx < RB * C4; idx += 256) {
                int r = idx / C4, c4 = idx % C4;
                int row = row0 + r;
                if (row >= n) row = n - 1;
                float4 v = ((const float4*)(X + (size_t)row * K + kc))[c4];
                if (BN) {
                    float4 sv = ((const float4*)(bnS + kc))[c4];
                    float4 tv = ((const float4*)(bnT + kc))[c4];
                    v.x = v.x * sv.x + tv.x;
                    v.y = v.y * sv.y + tv.y;
                    v.z = v.z * sv.z + tv.z;
                    v.w = v.w * sv.w + tv.w;
                }
                *(float4*)(&Xl[r][c4 * 4]) = v;
            }
        }
        __syncthreads();
#pragma unroll 8
        for (int k = 0; k < KC; ++k) {
            float4 w4 = *(const float4*)(&Wl[k][colg * 4]);
#pragma unroll
            for (int r = 0; r < RPT; ++r) {
                float xv = Xl[rowg * RPT + r][k];
                acc[r].x += xv * w4.x;
                acc[r].y += xv * w4.y;
                acc[r].z += xv * w4.z;
                acc[r].w += xv * w4.w;
            }
        }
        __syncthreads();
    }
#pragma unroll
    for (int r = 0; r < RPT; ++r) {
        int row = row0 + rowg * RPT + r;
        if (row < n) *(float4*)(H + (size_t)row * M + colg * 4) = acc[r];
    }
}

// ---------------- aggregation: y[i] = leaky( di*sum_{s in row(i)} dinv[s]*h[s] + di^2*h[i] + b )
// GROUP lanes per node, each lane owns 4 consecutive features.

template <int F, int GROUP>
__global__ __launch_bounds__(256) void agg_kernel(const float* __restrict__ h,
                                                  const int* __restrict__ rowptr,
                                                  const int* __restrict__ csr,
                                                  const float* __restrict__ dinv,
                                                  const float* __restrict__ bias,
                                                  float* __restrict__ y, int n) {
    constexpr int NPB = 256 / GROUP;
    const int g = threadIdx.x % GROUP;
    const int node = blockIdx.x * NPB + threadIdx.x / GROUP;
    if (node >= n) return;
    const int f0 = g * 4;
    const float di = dinv[node];
    const int e1 = rowptr[node + 1];
    float ax = 0.f, ay = 0.f, az = 0.f, aw = 0.f;
    for (int e = rowptr[node]; e < e1; ++e) {
        int s = csr[e];
        float w = dinv[s];
        const float4 hv = *(const float4*)(h + (size_t)s * F + f0);
        ax += w * hv.x;
        ay += w * hv.y;
        az += w * hv.z;
        aw += w * hv.w;
    }
    const float4 hs = *(const float4*)(h + (size_t)node * F + f0);
    const float4 b4 = *(const float4*)(bias + f0);
    const float dd = di * di;
    float rx = ax * di + dd * hs.x + b4.x;
    float ry = ay * di + dd * hs.y + b4.y;
    float rz = az * di + dd * hs.z + b4.z;
    float rw = aw * di + dd * hs.w + b4.w;
    rx = rx > 0.f ? rx : NEG_SLOPE * rx;
    ry = ry > 0.f ? ry : NEG_SLOPE * ry;
    rz = rz > 0.f ? rz : NEG_SLOPE * rz;
    rw = rw > 0.f ? rw : NEG_SLOPE * rw;
    float4 out;
    out.x = rx; out.y = ry; out.z = rz; out.w = rw;
    *(float4*)(y + (size_t)node * F + f0) = out;
}

// ---------------- BN statistics (sum, sumsq per feature) ----------------

template <int F>
__global__ __launch_bounds__(256) void stats_kernel(const float* __restrict__ y,
                                                    float* __restrict__ sum,
                                                    float* __restrict__ ssq, int n) {
    constexpr int RPS = 256 / F;  // rows per block-step
    __shared__ float smS[256], smQ[256];
    const int t = threadIdx.x;
    const int f = t % F;
    const int r0 = t / F;
    float s = 0.f, q = 0.f;
    for (int row = blockIdx.x * RPS + r0; row < n; row += gridDim.x * RPS) {
        float v = y[(size_t)row * F + f];
        s += v;
        q += v * v;
    }
    smS[t] = s;
    smQ[t] = q;
    __syncthreads();
    if (t < F) {
        float S = 0.f, Q = 0.f;
#pragma unroll
        for (int r = 0; r < RPS; ++r) {
            S += smS[t + r * F];
            Q += smQ[t + r * F];
        }
        atomicAdd(&sum[t], S);
        atomicAdd(&ssq[t], Q);
    }
}

__global__ void bnparam_kernel(const float* __restrict__ sum, const float* __restrict__ ssq,
                               const float* __restrict__ gamma, const float* __restrict__ beta,
                               float* __restrict__ S, float* __restrict__ T, int n, int F) {
    int f = threadIdx.x;
    if (f < F) {
        float m = sum[f] / (float)n;
        float var = ssq[f] / (float)n - m * m;
        float inv = rsqrtf(var + BN_EPS);
        float sc = gamma[f] * inv;
        S[f] = sc;
        T[f] = beta[f] - m * sc;
    }
}

// ---------------- launch ----------------

extern "C" void kernel_launch(void* const* d_in, const int* in_sizes, int n_in,
                              void* d_out, int out_size, void* d_ws, size_t ws_size,
                              hipStream_t stream) {
    const float* x = (const float*)d_in[0];
    const int* edges = (const int*)d_in[1];   // [2, E] int32 per harness convention
    const float* W1 = (const float*)d_in[3];
    const float* b1 = (const float*)d_in[4];
    const float* W2 = (const float*)d_in[5];
    const float* b2 = (const float*)d_in[6];
    const float* W3 = (const float*)d_in[7];
    const float* b3 = (const float*)d_in[8];
    const float* gamma1 = (const float*)d_in[9];
    const float* beta1 = (const float*)d_in[10];
    const float* gamma2 = (const float*)d_in[11];
    const float* beta2 = (const float*)d_in[12];

    const int N = in_sizes[0] / 128;
    const int E = in_sizes[1] / 2;
    const int* esrc = edges;
    const int* edst = edges + E;

    char* ws = (char*)d_ws;
    size_t off = 0;
    auto alloc = [&](size_t bytes) -> void* {
        void* p = ws + off;
        off = (off + bytes + 255) & ~(size_t)255;
        return p;
    };
    int* cnt = (int*)alloc((size_t)N * 4);
    int* rowptr = (int*)alloc((size_t)(N + 1) * 4);
    int* wofs = (int*)alloc((size_t)N * 4);
    float* dinv = (float*)alloc((size_t)N * 4);
    int* partials = (int*)alloc(1024 * 4);
    int* pofs = (int*)alloc(1024 * 4);
    float* stats = (float*)alloc(1024 * 4);
    int* csr = (int*)alloc((size_t)E * 4);
    float* bufA = (float*)alloc((size_t)N * 128 * 4);
    float* bufB = (float*)alloc((size_t)N * 128 * 4);

    float* sumA = stats;
    float* ssA = stats + 128;
    float* sA = stats + 256;
    float* tA = stats + 384;
    float* sumB = stats + 512;
    float* ssB = stats + 640;
    float* sB = stats + 768;
    float* tB = stats + 896;

    const int NB = (N + 1023) / 1024;

    // graph preprocessing: degree -> rowptr -> dinv -> CSR
    zero_kernel<<<(N + 255) / 256, 256, 0, stream>>>(cnt, stats, N);
    count_kernel<<<2048, 256, 0, stream>>>(edst, cnt, E);
    scan_block_kernel<<<NB, 1024, 0, stream>>>(cnt, rowptr, partials, N);
    scan_block_kernel<<<1, 1024, 0, stream>>>(partials, pofs, nullptr, NB);
    scan_add_kernel<<<(N + 255) / 256, 256, 0, stream>>>(rowptr, pofs, N, E);
    dinv_kernel<<<(N + 255) / 256, 256, 0, stream>>>(cnt, rowptr, dinv, wofs, N);
    scatter_kernel<<<2048, 256, 0, stream>>>(esrc, edst, wofs, csr, E);

    // layer 1: h = x @ W1 ; agg ; leaky ; (BN folded forward)
    gemm_kernel<128, 128, 64, 4, false><<<(N + 31) / 32, 256, 0, stream>>>(x, W1, nullptr, nullptr, bufA, N);
    agg_kernel<128, 32><<<(N + 7) / 8, 256, 0, stream>>>(bufA, rowptr, csr, dinv, b1, bufB, N);
    stats_kernel<128><<<256, 256, 0, stream>>>(bufB, sumA, ssA, N);
    bnparam_kernel<<<1, 128, 0, stream>>>(sumA, ssA, gamma1, beta1, sA, tA, N, 128);

    // layer 2: h = bn(y1) @ W2 ; agg ; leaky
    gemm_kernel<128, 64, 64, 4, true><<<(N + 63) / 64, 256, 0, stream>>>(bufB, W2, sA, tA, bufA, N);
    agg_kernel<64, 16><<<(N + 15) / 16, 256, 0, stream>>>(bufA, rowptr, csr, dinv, b2, bufB, N);
    stats_kernel<64><<<256, 256, 0, stream>>>(bufB, sumB, ssB, N);
    bnparam_kernel<<<1, 64, 0, stream>>>(sumB, ssB, gamma2, beta2, sB, tB, N, 64);

    // layer 3: h = bn(y2) @ W3 ; agg ; leaky -> d_out
    gemm_kernel<64, 8, 64, 1, true><<<(N + 127) / 128, 256, 0, stream>>>(bufB, W3, sB, tB, bufA, N);
    agg_kernel<8, 2><<<(N + 127) / 128, 256, 0, stream>>>(bufA, rowptr, csr, dinv, b3, (float*)d_out, N);
}